// Round 10
// baseline (157.162 us; speedup 1.0000x reference)
//
#include <hip/hip_runtime.h>
#include <math.h>

// Problem constants
#define B_   4
#define N_   4096
#define K_   32
#define C_   192
#define CH_  195          // C + 3 (logical GEMM K)
#define KPAD 224          // 7 x 32 ; g_Wp cols: 0..191=channels, 192..194=dp, 195..223=0
#define NKT6 6            // K-tiles in LDS (kt=6 built from s_d in registers)
#define NNT16 16          // N-tiles per iteration (256 cols = 4 pairs)
#define GRID 256          // 1 block per CU (quasi-persistent)

using half8  = __attribute__((ext_vector_type(8))) _Float16;
using half2v = __attribute__((ext_vector_type(2))) _Float16;
using f32x4  = __attribute__((ext_vector_type(4))) float;

// Module-static device scratch
__device__ _Float16 g_Wp[C_ * KPAD];                    // 86016 B (rows pre-scaled by BN inv)
__device__ _Float16 g_xT[(size_t)B_ * N_ * C_];         // 6291456 B

// ---- fused prep: blocks 0..511 transpose x -> g_xT ; blocks 512.. convert W ----
// g_Wp row o, col r: r<192 -> W[o][3+r] (channels), 192..194 -> W[o][r-192] (dp), else 0.
__global__ __launch_bounds__(256) void prep(const float* __restrict__ x,
                                            const float* __restrict__ W,
                                            const float* __restrict__ gamma_,
                                            const float* __restrict__ rvar) {
    const int tid = threadIdx.x;
    if (blockIdx.x < 512) {
        __shared__ float s[32][201];
        const int b  = blockIdx.x >> 7;          // 4 batches x 128 tiles
        const int n0 = (blockIdx.x & 127) * 32;
        const int cl = tid >> 3;                 // 0..31 channel-within-iter
        const int n4 = (tid & 7) * 4;            // 0..28, x4 floats
#pragma unroll
        for (int it = 0; it < 6; ++it) {
            const int c = it * 32 + cl;
            const float4 v = *(const float4*)(x + ((size_t)b * C_ + c) * N_ + n0 + n4);
            s[n4 + 0][c] = v.x; s[n4 + 1][c] = v.y; s[n4 + 2][c] = v.z; s[n4 + 3][c] = v.w;
        }
        __syncthreads();
        const int n  = tid >> 3;                 // 0..31
        const int og = tid & 7;                  // octet-group
#pragma unroll
        for (int it = 0; it < 3; ++it) {
            const int oc = it * 8 + og;          // 0..23 channel octet
            half8 v;
#pragma unroll
            for (int jj = 0; jj < 8; ++jj) v[jj] = (_Float16)s[n][oc * 8 + jj];
            *(half8*)(g_xT + ((size_t)b * N_ + n0 + n) * C_ + oc * 8) = v;
        }
    } else {
        const int i = (blockIdx.x - 512) * 256 + tid;
        if (i < C_ * KPAD) {
            const int o = i / KPAD, r = i - o * KPAD;
            const float inv = gamma_[o] * rsqrtf(rvar[o] + 1e-5f);  // BN scale folded into W
            float v = 0.0f;
            if (r < 192)      v = W[o * CH_ + 3 + r];      // channel weights
            else if (r < 195) v = W[o * CH_ + (r - 192)];  // dp weights
            g_Wp[i] = (_Float16)(v * inv);
        }
    }
}

// ---- main fused kernel (R10): 512 threads, 1 block/CU, 4 PAIRS PER PHASE ----
// Bytes-per-pair is the binding resource (R9 evidence: W-halving -> 7100->6080
// cyc/pair). This config: W stream 43->21.5 KB/pair (8 waves share one pass; waves
// w and w+4 read identical W addrs -> L1 hits), sin/pair halves (512 thr build 256
// cols), bf LDS reads/pair ~halve, stores full-line via 16-point s_out staging
// (write-amp 4x -> 1x). acc[3][8]=96/wave; __launch_bounds__(512,2) caps 256 regs
// (R9 allocated same pressure cleanly at cap 256). LDS ~128 KB -> 1 block/CU.
__global__ __launch_bounds__(512, 2) void la_mfma(
    const float* __restrict__ p,      // [B,N,3]
    const int*   __restrict__ idx,    // [B,N,K]
    const float* __restrict__ gamma_,
    const float* __restrict__ beta_,
    const float* __restrict__ rmean,
    const float* __restrict__ rvar,
    float* __restrict__ out)          // [B,C,N]
{
    __shared__ _Float16 hb[7 * NNT16 * 64 * 8];     // 114688 B
    __shared__ float s_d[3][256];                   // per-col dp (kt=6 built in regs)
    __shared__ float s_out[C_][16];                 // 16-point store window (12 KB)
    __shared__ float s_bias[C_], s_fr[32];

    const int tid  = threadIdx.x;
    const int lane = tid & 63;
    const int w    = tid >> 6;        // 0..7
    const int l15  = lane & 15;
    const int quad = lane >> 4;

    // XCD-chunked: xcd owns pairs [xcd*1024, +1024); 32 blocks/xcd x 32 pairs each.
    const int xcd      = blockIdx.x & 7;
    const int slot     = blockIdx.x >> 3;              // 0..31
    const int pairbase = xcd * 1024 + slot * 32;
    const int iters    = 8;                            // 8 x 4 pairs = 32
    const int b        = xcd >> 1;

    if (tid < C_) {
        const float inv = gamma_[tid] * rsqrtf(rvar[tid] + 1e-5f);
        s_bias[tid] = beta_[tid] - rmean[tid] * inv;   // scale part lives in g_Wp
    }
    // s_fr[f] = (50 / 2pi) * 500^(-f/32)   (v_sin takes revolutions)
    if (tid < 32) s_fr[tid] = 7.9577471546f * exp2f(-(float)tid * 0.2801808715263400f);
    __syncthreads();

    float sfr[8];
#pragma unroll
    for (int jj = 0; jj < 8; ++jj) sfr[jj] = s_fr[quad * 8 + jj];

    // column tiles owned by this thread in phase B: T0 = w (sb=0), T1 = 8+w (sb=1).
    // tile T: pair offset pp = T>>2, point pt = (T>>1)&1, k = (T&1)*16 + l15.
    const int k0v = (w & 1) * 16 + l15;    // same for T0 and T1 (T&1 == w&1)
    const int pp0 = w >> 2,        pt0 = (w >> 1) & 1;
    const int pp1 = (8 + w) >> 2,  pt1 = ((8 + w) >> 1) & 1;

    // prefetch gather indices for iteration 0 (2 scalars — safe)
    int j0 = idx[(size_t)((pairbase + pp0) * 2 + pt0) * K_ + k0v];
    int j1 = idx[(size_t)((pairbase + pp1) * 2 + pt1) * K_ + k0v];

    for (int it = 0; it < iters; ++it) {
        const int pr0 = pairbase + 4 * it;

        // ---- Phase B: build 256 cols (4 pairs) into hb ----
        auto build = [&](int T, int jv, int pp, int pt) {
            const int gp = (pr0 + pp) * 2 + pt;
            const float d0 = p[(size_t)(b * N_ + jv) * 3 + 0] - p[(size_t)gp * 3 + 0];
            const float d1 = p[(size_t)(b * N_ + jv) * 3 + 1] - p[(size_t)gp * 3 + 1];
            const float d2 = p[(size_t)(b * N_ + jv) * 3 + 2] - p[(size_t)gp * 3 + 2];
            const _Float16* xh = g_xT + ((size_t)b * N_ + jv) * C_;
#pragma unroll
            for (int i6 = 0; i6 < 6; ++i6) {
                const int chunk = quad + 4 * i6;           // channel octet 0..23; kt = i6
                const half8 v = *(const half8*)(xh + chunk * 8);
                const float dd  = (chunk < 8) ? d0 : ((chunk < 16) ? d1 : d2);
                const float off = (chunk & 4) ? 0.25f : 0.0f;   // cos = sin(+1/4 rev)
                half8 hv;
#pragma unroll
                for (int jj = 0; jj < 8; jj += 2) {
                    const float pe0 = __builtin_amdgcn_sinf(fmaf(dd, sfr[jj],     off));
                    const float pe1 = __builtin_amdgcn_sinf(fmaf(dd, sfr[jj + 1], off));
                    const half2v pe2 = __builtin_bit_cast(half2v, __builtin_amdgcn_cvt_pkrtz(pe0, pe1));
                    half2v v2; v2[0] = v[jj]; v2[1] = v[jj + 1];
                    const half2v r2 = pe2 * v2 + pe2;   // v_pk_fma_f16: pe*(x+1)
                    hv[jj] = r2[0]; hv[jj + 1] = r2[1];
                }
                *(half8*)(&hb[(size_t)((i6 * NNT16 + T) * 64 + quad * 16 + l15) * 8]) = hv;
            }
            if (quad == 0) {     // dp for col -> s_d (kt=6 built in regs at consume)
                const int col = T * 16 + l15;
                s_d[0][col] = d0; s_d[1][col] = d1; s_d[2][col] = d2;
            }
        };
        build(w,     j0, pp0, pt0);
        build(8 + w, j1, pp1, pt1);
        __syncthreads();        // hb + s_d complete

        // prefetch next iteration's gather indices under phase C (2 scalars)
        int jn0 = j0, jn1 = j1;
        if (it + 1 < iters) {
            jn0 = idx[(size_t)((pr0 + 4 + pp0) * 2 + pt0) * K_ + k0v];
            jn1 = idx[(size_t)((pr0 + 4 + pp1) * 2 + pt1) * K_ + k0v];
        }

        // ---- Phase C: transposed MFMA; wave (w&3) -> row-tiles, (w>>2) -> n-half ----
        const int rg = (w & 3) * 3;            // row-tile base (x16 = channel base)
        const int tb = (w >> 2) * 8;           // n-tile base
        f32x4 acc[3][8];
#pragma unroll
        for (int i = 0; i < 3; ++i)
#pragma unroll
            for (int t = 0; t < 8; ++t) acc[i][t] = (f32x4)0.0f;

#pragma unroll
        for (int kt = 0; kt < NKT6; ++kt) {
            const int kk0 = kt * 32 + quad * 8;
            half8 a[3];
#pragma unroll
            for (int i = 0; i < 3; ++i)
                a[i] = *(const half8*)(g_Wp + (size_t)((rg + i) * 16 + l15) * KPAD + kk0);
#pragma unroll
            for (int tt = 0; tt < 8; ++tt) {
                const half8 bf = *(const half8*)(&hb[(size_t)((kt * NNT16 + tb + tt) * 64 + lane) * 8]);
#pragma unroll
                for (int i = 0; i < 3; ++i)   // A=h-frag, B=W-frag -> D = (W.h)^T
                    acc[i][tt] = __builtin_amdgcn_mfma_f32_16x16x32_f16(bf, a[i], acc[i][tt], 0, 0, 0);
            }
        }
        // kt = 6: dp rows 192..194 (only quad 0's k-octet 0..7 has nonzero rows)
        {
            half8 a6[3];
#pragma unroll
            for (int i = 0; i < 3; ++i)
                a6[i] = *(const half8*)(g_Wp + (size_t)((rg + i) * 16 + l15) * KPAD + 6 * 32 + quad * 8);
#pragma unroll
            for (int tt = 0; tt < 8; ++tt) {
                const int col = (tb + tt) * 16 + l15;
                half8 b6 = (half8)(_Float16)0.0f;
                const float e0 = s_d[0][col];   // quads read same addr -> broadcast
                const float e1 = s_d[1][col];
                const float e2 = s_d[2][col];
                if (quad == 0) {
                    b6[0] = (_Float16)e0; b6[1] = (_Float16)e1; b6[2] = (_Float16)e2;
                }
#pragma unroll
                for (int i = 0; i < 3; ++i)
                    acc[i][tt] = __builtin_amdgcn_mfma_f32_16x16x32_f16(b6, a6[i], acc[i][tt], 0, 0, 0);
            }
        }

        // ---- Epilogue: acc[i][tt] covers cols (tb+tt)*16 + quad*4 + r ----
        // point P = (tb+tt)>>1 (tt pairs), k = ((tb+tt)&1)*16 + quad*4 + r.
        // max over 32 k: 8 in-lane + xor16 + xor32. Window slot = (it&1)*8 + local P.
        const int pbase = (it & 1) * 8 + (w >> 2) * 4;
#pragma unroll
        for (int i = 0; i < 3; ++i) {
            const int m = (rg + i) * 16 + l15;
#pragma unroll
            for (int qq = 0; qq < 4; ++qq) {
                const f32x4 va = acc[i][2 * qq];
                const f32x4 vb = acc[i][2 * qq + 1];
                float v = fmaxf(fmaxf(fmaxf(va[0], va[1]), fmaxf(va[2], va[3])),
                                fmaxf(fmaxf(vb[0], vb[1]), fmaxf(vb[2], vb[3])));
                v = fmaxf(v, __shfl_xor(v, 16, 64));
                v = fmaxf(v, __shfl_xor(v, 32, 64));
                if (quad == 0)
                    s_out[m][pbase + qq] = fmaxf(v + s_bias[m], 0.0f);
            }
        }
        __syncthreads();   // s_out halves complete; hb/s_d reads done before next build

        // ---- flush full 64B lines every 2nd iteration (write-amp 1x) ----
        if (it & 1) {
            const int n0w = ((pr0 - 4) * 2) & (N_ - 1);   // window = pairs pr0-4 .. pr0+3
#pragma unroll
            for (int ss = 0; ss < 2; ++ss) {
                const int t = ss * 512 + tid;
                if (t < C_ * 4) {
                    const int row = t >> 2, c4 = (t & 3) * 4;
                    const float4 o4 = *(const float4*)(&s_out[row][c4]);
                    *(float4*)(&out[((size_t)b * C_ + row) * N_ + n0w + c4]) = o4;
                }
            }
        }

        j0 = jn0; j1 = jn1;
    }
}

extern "C" void kernel_launch(void* const* d_in, const int* in_sizes, int n_in,
                              void* d_out, int out_size, void* d_ws, size_t ws_size,
                              hipStream_t stream) {
    (void)in_sizes; (void)n_in; (void)out_size; (void)d_ws; (void)ws_size;
    const float* p      = (const float*)d_in[0];
    const float* x      = (const float*)d_in[1];
    const int*   idx    = (const int*)d_in[2];
    const float* W      = (const float*)d_in[3];
    const float* gamma_ = (const float*)d_in[4];
    const float* beta_  = (const float*)d_in[5];
    const float* rmean  = (const float*)d_in[6];
    const float* rvar   = (const float*)d_in[7];
    float* out = (float*)d_out;

    prep<<<512 + (C_ * KPAD + 255) / 256, 256, 0, stream>>>(x, W, gamma_, rvar);
    la_mfma<<<GRID, 512, 0, stream>>>(p, idx, gamma_, beta_, rmean, rvar, out);
}